// Round 9
// baseline (996.620 us; speedup 1.0000x reference)
//
#include <hip/hip_runtime.h>
#include <hip/hip_bf16.h>

#define EPSV 1e-5f

typedef short short8v __attribute__((ext_vector_type(8)));
typedef float f32x4 __attribute__((ext_vector_type(4)));

// ---------- bf16 helpers ----------
__device__ __forceinline__ unsigned short f2bf(float f){ // RNE
  unsigned u = __float_as_uint(f);
  unsigned r = u + 0x7fffu + ((u >> 16) & 1u);
  return (unsigned short)(r >> 16);
}
__device__ __forceinline__ unsigned pk2bf(float x, float y){
  return (unsigned)f2bf(x) | ((unsigned)f2bf(y) << 16);
}
__device__ __forceinline__ float bf2f(unsigned short s){
  return __uint_as_float(((unsigned)s) << 16);
}
__device__ __forceinline__ float bflo(unsigned u){ return __uint_as_float(u << 16); }
__device__ __forceinline__ float bfhi(unsigned u){ return __uint_as_float(u & 0xffff0000u); }

// ---------------- degree histogram ----------------
__global__ void hist_kernel(const int* __restrict__ dst, int* __restrict__ deg, int E){
  int i = blockIdx.x*256 + threadIdx.x;
  if (i < E) atomicAdd(&deg[dst[i]], 1);
}

// ---------------- scan ----------------
__global__ void scan_partial(const int* __restrict__ deg, int* __restrict__ bsums, int N){
  __shared__ int sd[256];
  int t = threadIdx.x;
  int base = blockIdx.x*1024 + t*4;
  int s = 0;
  if (base+0 < N) s += deg[base+0];
  if (base+1 < N) s += deg[base+1];
  if (base+2 < N) s += deg[base+2];
  if (base+3 < N) s += deg[base+3];
  sd[t]=s; __syncthreads();
  for (int off=128; off>0; off>>=1){
    if (t<off) sd[t]+=sd[t+off];
    __syncthreads();
  }
  if (t==0) bsums[blockIdx.x]=sd[0];
}

__global__ void scan_bsums(int* bsums, int* row_start, int B, int N, int E){
  if (threadIdx.x==0 && blockIdx.x==0){
    int run=0;
    for (int b=0;b<B;b++){ int v=bsums[b]; bsums[b]=run; run+=v; }
    row_start[N]=E;
  }
}

// scan_final + dinv fused
__global__ void scan_final(const int* __restrict__ deg, const int* __restrict__ bsums,
                           int* __restrict__ row_start, int* __restrict__ cursor,
                           float* __restrict__ dinv, int N){
  __shared__ int sd[256];
  int t=threadIdx.x, b=blockIdx.x;
  int base=b*1024+t*4;
  int v0=0,v1=0,v2=0,v3=0;
  if (base+0<N) v0=deg[base+0];
  if (base+1<N) v1=deg[base+1];
  if (base+2<N) v2=deg[base+2];
  if (base+3<N) v3=deg[base+3];
  int s=v0+v1+v2+v3;
  sd[t]=s; __syncthreads();
  for (int off=1; off<256; off<<=1){
    int x = (t>=off)?sd[t-off]:0;
    __syncthreads();
    sd[t]+=x;
    __syncthreads();
  }
  int excl = sd[t]-s + bsums[b];
  int e0=excl, e1=excl+v0, e2=e1+v1, e3=e2+v2;
  if (base+0<N){ row_start[base+0]=e0; cursor[base+0]=e0; dinv[base+0]=rsqrtf((float)v0+1.0f); }
  if (base+1<N){ row_start[base+1]=e1; cursor[base+1]=e1; dinv[base+1]=rsqrtf((float)v1+1.0f); }
  if (base+2<N){ row_start[base+2]=e2; cursor[base+2]=e2; dinv[base+2]=rsqrtf((float)v2+1.0f); }
  if (base+3<N){ row_start[base+3]=e3; cursor[base+3]=e3; dinv[base+3]=rsqrtf((float)v3+1.0f); }
}

__global__ void scatter_kernel(const int* __restrict__ src, const int* __restrict__ dst,
                               int* __restrict__ cursor, int* __restrict__ csr_src, int E){
  int i = blockIdx.x*256 + threadIdx.x;
  if (i < E){
    int d = dst[i];
    int pos = atomicAdd(&cursor[d], 1);
    csr_src[pos] = src[i];
  }
}

// ---------------- degree-sort (counting sort, 64 bins) ----------------
__global__ void deghist_kernel(const int* __restrict__ deg, int* __restrict__ dhist, int N){
  __shared__ int sb[64];
  int t = threadIdx.x;
  if (t < 64) sb[t] = 0;
  __syncthreads();
  int i = blockIdx.x*256 + t;
  if (i < N){
    int b = deg[i]; if (b > 63) b = 63;
    atomicAdd(&sb[b], 1);
  }
  __syncthreads();
  if (t < 64 && sb[t] != 0) atomicAdd(&dhist[t], sb[t]);
}

__global__ void degscan_kernel(const int* __restrict__ dhist, int* __restrict__ dcur){
  if (threadIdx.x == 0 && blockIdx.x == 0){
    int run = 0;
    for (int b=0;b<64;b++){ int v = dhist[b]; dcur[b] = run; run += v; }
  }
}

__global__ void degscatter_kernel(const int* __restrict__ deg, int* __restrict__ dcur,
                                  int* __restrict__ perm, int N){
  int i = blockIdx.x*256 + threadIdx.x;
  if (i < N){
    int b = deg[i]; if (b > 63) b = 63;
    int pos = atomicAdd(&dcur[b], 1);
    perm[pos] = i;
  }
}

// ---------------- W pre-convert: W[D x 128] fp32 -> WT [128 x Dpad] bf16 ----------------
__global__ void wsplit_kernel(const float* __restrict__ W, unsigned short* __restrict__ WT,
                              int D, int Dpad){
  int k = blockIdx.x*256 + threadIdx.x;
  int c = blockIdx.y;
  if (k >= Dpad) return;
  float v = (k < D) ? W[(size_t)k*128 + c] : 0.f;
  WT[(size_t)c*Dpad + k] = f2bf(v);
}

// fused small-weight convert: z=0 -> w2T, z=1 -> w3T, z=2 -> aw1 hi/lo
__global__ void wsplit_all(const float* __restrict__ W2, const float* __restrict__ W3,
                           const float* __restrict__ WA,
                           unsigned short* __restrict__ w2T, unsigned short* __restrict__ w3T,
                           unsigned short* __restrict__ aT_hi, unsigned short* __restrict__ aT_lo){
  int k = threadIdx.x;
  int c = blockIdx.y;
  int z = blockIdx.z;
  if (z == 0){
    w2T[c*128 + k] = f2bf(W2[(size_t)k*128 + c]);
  } else if (z == 1){
    w3T[c*128 + k] = f2bf(W3[(size_t)k*128 + c]);
  } else {
    float v = WA[(size_t)k*128 + c];
    unsigned short h = f2bf(v);
    aT_hi[c*128 + k] = h;
    aT_lo[c*128 + k] = f2bf(v - bf2f(h));
  }
}

// ---------------- GEMM1: A fp32 concat -> bf16 out, register prefetch ----------------
#define LOADA(KC) { \
  const int gk0 = (KC) + akseg; \
  if ((Rst < N) && (gk0 + 32 <= Da)){ \
    const float4* p4 = (const float4*)(xa + (size_t)Rst*Da + gk0); \
    pa0=p4[0]; pa1=p4[1]; pa2=p4[2]; pa3=p4[3]; pa4=p4[4]; pa5=p4[5]; pa6=p4[6]; pa7=p4[7]; \
  } else { \
    float tmp[32]; \
    _Pragma("unroll") \
    for (int q=0;q<32;q++){ \
      int gk = gk0 + q; float x = 0.f; \
      if (Rst < N){ \
        if (gk < Da) x = xa[(size_t)Rst*Da + gk]; \
        else if (gk < D) x = xb[(size_t)Rst*Db + (gk - Da)]; \
      } \
      tmp[q]=x; } \
    pa0=*(float4*)&tmp[0];  pa1=*(float4*)&tmp[4];  pa2=*(float4*)&tmp[8];  pa3=*(float4*)&tmp[12]; \
    pa4=*(float4*)&tmp[16]; pa5=*(float4*)&tmp[20]; pa6=*(float4*)&tmp[24]; pa7=*(float4*)&tmp[28]; \
  } }

#define LOADW(KC) { \
  const unsigned short* ph = wrowp + (KC); \
  pw0=*(const uint4*)(ph); pw1=*(const uint4*)(ph+8); pw2=*(const uint4*)(ph+16); pw3=*(const uint4*)(ph+24); }

__global__ __launch_bounds__(256, 3) void gemm_mfma_kernel(
    const float* __restrict__ xa, const float* __restrict__ xb,
    const unsigned short* __restrict__ WT,
    unsigned short* __restrict__ outb, int N, int Da, int Db, int Dpad)
{
  __shared__ unsigned short Abf[128*64];
  __shared__ unsigned short Bbf[128*64];

  const int tid  = threadIdx.x;
  const int lane = tid & 63;
  const int wave = tid >> 6;
  const int lr   = lane & 15;
  const int kg   = lane >> 4;
  const int rowBase = blockIdx.x * 128;
  const int D = Da + Db;

  f32x4 acc[2][8];
  #pragma unroll
  for (int s=0;s<2;s++)
    #pragma unroll
    for (int c=0;c<8;c++){ acc[s][c][0]=0.f; acc[s][c][1]=0.f; acc[s][c][2]=0.f; acc[s][c][3]=0.f; }

  const int arow = tid >> 1;
  const int akseg = (tid & 1) * 32;
  const int Rst = rowBase + arow;
  const int abase = arow*128 + akseg*2;
  const int aswz  = (arow & 7) << 4;
  const unsigned short* wrowp = WT + (size_t)arow*Dpad + akseg;

  float4 pa0,pa1,pa2,pa3,pa4,pa5,pa6,pa7;
  uint4  pw0,pw1,pw2,pw3;

  LOADA(0)
  LOADW(0)

  for (int kc = 0; kc < Dpad; kc += 64){
    __syncthreads();
    {
      unsigned u[4];
      u[0]=pk2bf(pa0.x,pa0.y); u[1]=pk2bf(pa0.z,pa0.w); u[2]=pk2bf(pa1.x,pa1.y); u[3]=pk2bf(pa1.z,pa1.w);
      *(uint4*)((char*)Abf + ((abase+ 0)^aswz)) = *(const uint4*)u;
      u[0]=pk2bf(pa2.x,pa2.y); u[1]=pk2bf(pa2.z,pa2.w); u[2]=pk2bf(pa3.x,pa3.y); u[3]=pk2bf(pa3.z,pa3.w);
      *(uint4*)((char*)Abf + ((abase+16)^aswz)) = *(const uint4*)u;
      u[0]=pk2bf(pa4.x,pa4.y); u[1]=pk2bf(pa4.z,pa4.w); u[2]=pk2bf(pa5.x,pa5.y); u[3]=pk2bf(pa5.z,pa5.w);
      *(uint4*)((char*)Abf + ((abase+32)^aswz)) = *(const uint4*)u;
      u[0]=pk2bf(pa6.x,pa6.y); u[1]=pk2bf(pa6.z,pa6.w); u[2]=pk2bf(pa7.x,pa7.y); u[3]=pk2bf(pa7.z,pa7.w);
      *(uint4*)((char*)Abf + ((abase+48)^aswz)) = *(const uint4*)u;
      *(uint4*)((char*)Bbf + ((abase+ 0)^aswz)) = pw0;
      *(uint4*)((char*)Bbf + ((abase+16)^aswz)) = pw1;
      *(uint4*)((char*)Bbf + ((abase+32)^aswz)) = pw2;
      *(uint4*)((char*)Bbf + ((abase+48)^aswz)) = pw3;
    }
    __syncthreads();
    const int kn = kc + 64;
    if (kn < Dpad){
      LOADA(kn)
      LOADW(kn)
    }
    #pragma unroll
    for (int ks=0; ks<2; ks++){
      const int kb = ks*64 + kg*16;
      const int r0 = wave*32 + lr;
      const int r1 = r0 + 16;
      const int offA0 = (r0*128 + kb) ^ ((r0&7)<<4);
      const int offA1 = (r1*128 + kb) ^ ((r1&7)<<4);
      short8v a0 = *(const short8v*)((const char*)Abf + offA0);
      short8v a1 = *(const short8v*)((const char*)Abf + offA1);
      #pragma unroll
      for (int ct=0; ct<8; ct++){
        const int c = ct*16 + lr;
        const int offB = (c*128 + kb) ^ ((c&7)<<4);
        short8v b = *(const short8v*)((const char*)Bbf + offB);
        acc[0][ct] = __builtin_amdgcn_mfma_f32_16x16x32_bf16(a0, b, acc[0][ct], 0,0,0);
        acc[1][ct] = __builtin_amdgcn_mfma_f32_16x16x32_bf16(a1, b, acc[1][ct], 0,0,0);
      }
    }
  }
  const int wrow = rowBase + wave*32;
  #pragma unroll
  for (int strip=0; strip<2; strip++){
    #pragma unroll
    for (int ct=0; ct<8; ct++){
      #pragma unroll
      for (int i=0;i<4;i++){
        int R = wrow + strip*16 + kg*4 + i;
        int C = ct*16 + lr;
        if (R < N) outb[(size_t)R*128 + C] = f2bf(acc[strip][ct][i]);
      }
    }
  }
}

// ---------------- GEMM2/3: A bf16 [N x 128] -> bf16 out ----------------
__global__ __launch_bounds__(256, 3) void gemm_bf16_kernel(
    const unsigned short* __restrict__ xa,
    const unsigned short* __restrict__ WT,
    unsigned short* __restrict__ outb, int N)
{
  __shared__ unsigned short Abf[128*64];
  __shared__ unsigned short Bbf[128*64];

  const int tid  = threadIdx.x;
  const int lane = tid & 63;
  const int wave = tid >> 6;
  const int lr   = lane & 15;
  const int kg   = lane >> 4;
  const int rowBase = blockIdx.x * 128;

  f32x4 acc[2][8];
  #pragma unroll
  for (int s=0;s<2;s++)
    #pragma unroll
    for (int c=0;c<8;c++){ acc[s][c][0]=0.f; acc[s][c][1]=0.f; acc[s][c][2]=0.f; acc[s][c][3]=0.f; }

  const int arow = tid >> 1;
  const int akseg = (tid & 1) * 32;
  const int Rst = rowBase + arow;
  const int abase = arow*128 + akseg*2;
  const int aswz  = (arow & 7) << 4;
  const unsigned short* arp = xa + (size_t)Rst*128 + akseg;
  const unsigned short* wrp = WT + (size_t)arow*128 + akseg;

  uint4 pa0,pa1,pa2,pa3, pw0,pw1,pw2,pw3;
  uint4 z4; z4.x=0; z4.y=0; z4.z=0; z4.w=0;
  if (Rst < N){ pa0=*(const uint4*)(arp); pa1=*(const uint4*)(arp+8); pa2=*(const uint4*)(arp+16); pa3=*(const uint4*)(arp+24); }
  else { pa0=z4; pa1=z4; pa2=z4; pa3=z4; }
  pw0=*(const uint4*)(wrp); pw1=*(const uint4*)(wrp+8); pw2=*(const uint4*)(wrp+16); pw3=*(const uint4*)(wrp+24);

  #pragma unroll
  for (int kc = 0; kc < 128; kc += 64){
    __syncthreads();
    *(uint4*)((char*)Abf + ((abase+ 0)^aswz)) = pa0;
    *(uint4*)((char*)Abf + ((abase+16)^aswz)) = pa1;
    *(uint4*)((char*)Abf + ((abase+32)^aswz)) = pa2;
    *(uint4*)((char*)Abf + ((abase+48)^aswz)) = pa3;
    *(uint4*)((char*)Bbf + ((abase+ 0)^aswz)) = pw0;
    *(uint4*)((char*)Bbf + ((abase+16)^aswz)) = pw1;
    *(uint4*)((char*)Bbf + ((abase+32)^aswz)) = pw2;
    *(uint4*)((char*)Bbf + ((abase+48)^aswz)) = pw3;
    __syncthreads();
    if (kc == 0){
      if (Rst < N){ pa0=*(const uint4*)(arp+64); pa1=*(const uint4*)(arp+72); pa2=*(const uint4*)(arp+80); pa3=*(const uint4*)(arp+88); }
      pw0=*(const uint4*)(wrp+64); pw1=*(const uint4*)(wrp+72); pw2=*(const uint4*)(wrp+80); pw3=*(const uint4*)(wrp+88);
    }
    #pragma unroll
    for (int ks=0; ks<2; ks++){
      const int kb = ks*64 + kg*16;
      const int r0 = wave*32 + lr;
      const int r1 = r0 + 16;
      const int offA0 = (r0*128 + kb) ^ ((r0&7)<<4);
      const int offA1 = (r1*128 + kb) ^ ((r1&7)<<4);
      short8v a0 = *(const short8v*)((const char*)Abf + offA0);
      short8v a1 = *(const short8v*)((const char*)Abf + offA1);
      #pragma unroll
      for (int ct=0; ct<8; ct++){
        const int c = ct*16 + lr;
        const int offB = (c*128 + kb) ^ ((c&7)<<4);
        short8v b = *(const short8v*)((const char*)Bbf + offB);
        acc[0][ct] = __builtin_amdgcn_mfma_f32_16x16x32_bf16(a0, b, acc[0][ct], 0,0,0);
        acc[1][ct] = __builtin_amdgcn_mfma_f32_16x16x32_bf16(a1, b, acc[1][ct], 0,0,0);
      }
    }
  }
  const int wrow = rowBase + wave*32;
  #pragma unroll
  for (int strip=0; strip<2; strip++){
    #pragma unroll
    for (int ct=0; ct<8; ct++){
      #pragma unroll
      for (int i=0;i<4;i++){
        int R = wrow + strip*16 + kg*4 + i;
        int C = ct*16 + lr;
        if (R < N) outb[(size_t)R*128 + C] = f2bf(acc[strip][ct][i]);
      }
    }
  }
}

// ---------------- attention + pooling fused ----------------
__global__ __launch_bounds__(256) void att_pool_kernel(
    const unsigned short* __restrict__ xa,
    const unsigned short* __restrict__ WhiT, const unsigned short* __restrict__ WloT,
    const float* __restrict__ b1, const float* __restrict__ w2, const float* __restrict__ b2,
    const int* __restrict__ batch,
    float* __restrict__ pooled, float* __restrict__ denom, int N)
{
  __shared__ unsigned short Abf[128*64];
  __shared__ unsigned short Bhi[128*64];
  __shared__ unsigned short Blo[128*64];
  __shared__ float sden[8];
  __shared__ float sAex[128];
  __shared__ int   sBatch[128];

  const int tid  = threadIdx.x;
  const int lane = tid & 63;
  const int wave = tid >> 6;
  const int lr   = lane & 15;
  const int kg   = lane >> 4;
  const int rowBase = blockIdx.x * 128;

  if (tid < 8) sden[tid] = 0.f;
  if (tid < 128){
    int R = rowBase + tid;
    sBatch[tid] = (R < N) ? batch[R] : -1;
  }

  f32x4 acc[2][8];
  #pragma unroll
  for (int s=0;s<2;s++)
    #pragma unroll
    for (int c=0;c<8;c++){ acc[s][c][0]=0.f; acc[s][c][1]=0.f; acc[s][c][2]=0.f; acc[s][c][3]=0.f; }

  const int arow = tid >> 1;
  const int akseg = (tid & 1) * 32;
  const int Rst = rowBase + arow;
  const int abase = arow*128 + akseg*2;
  const int aswz  = (arow & 7) << 4;
  const unsigned short* arp = xa + (size_t)Rst*128 + akseg;

  #pragma unroll
  for (int kc = 0; kc < 128; kc += 64){
    __syncthreads();
    {
      uint4 z4; z4.x=0; z4.y=0; z4.z=0; z4.w=0;
      uint4 a0=z4,a1=z4,a2=z4,a3=z4;
      if (Rst < N){
        a0=*(const uint4*)(arp+kc); a1=*(const uint4*)(arp+kc+8);
        a2=*(const uint4*)(arp+kc+16); a3=*(const uint4*)(arp+kc+24);
      }
      *(uint4*)((char*)Abf + ((abase+ 0)^aswz)) = a0;
      *(uint4*)((char*)Abf + ((abase+16)^aswz)) = a1;
      *(uint4*)((char*)Abf + ((abase+32)^aswz)) = a2;
      *(uint4*)((char*)Abf + ((abase+48)^aswz)) = a3;
      const unsigned short* ph = WhiT + (size_t)arow*128 + kc + akseg;
      const unsigned short* pl = WloT + (size_t)arow*128 + kc + akseg;
      *(uint4*)((char*)Bhi + ((abase+ 0)^aswz)) = *(const uint4*)(ph);
      *(uint4*)((char*)Bhi + ((abase+16)^aswz)) = *(const uint4*)(ph+8);
      *(uint4*)((char*)Bhi + ((abase+32)^aswz)) = *(const uint4*)(ph+16);
      *(uint4*)((char*)Bhi + ((abase+48)^aswz)) = *(const uint4*)(ph+24);
      *(uint4*)((char*)Blo + ((abase+ 0)^aswz)) = *(const uint4*)(pl);
      *(uint4*)((char*)Blo + ((abase+16)^aswz)) = *(const uint4*)(pl+8);
      *(uint4*)((char*)Blo + ((abase+32)^aswz)) = *(const uint4*)(pl+16);
      *(uint4*)((char*)Blo + ((abase+48)^aswz)) = *(const uint4*)(pl+24);
    }
    __syncthreads();
    #pragma unroll
    for (int ks=0; ks<2; ks++){
      const int kb = ks*64 + kg*16;
      const int r0 = wave*32 + lr;
      const int r1 = r0 + 16;
      const int offA0 = (r0*128 + kb) ^ ((r0&7)<<4);
      const int offA1 = (r1*128 + kb) ^ ((r1&7)<<4);
      short8v a0 = *(const short8v*)((const char*)Abf + offA0);
      short8v a1 = *(const short8v*)((const char*)Abf + offA1);
      #pragma unroll
      for (int ct=0; ct<8; ct++){
        const int c = ct*16 + lr;
        const int offB = (c*128 + kb) ^ ((c&7)<<4);
        short8v bh = *(const short8v*)((const char*)Bhi + offB);
        short8v bl = *(const short8v*)((const char*)Blo + offB);
        acc[0][ct] = __builtin_amdgcn_mfma_f32_16x16x32_bf16(a0, bh, acc[0][ct], 0,0,0);
        acc[0][ct] = __builtin_amdgcn_mfma_f32_16x16x32_bf16(a0, bl, acc[0][ct], 0,0,0);
        acc[1][ct] = __builtin_amdgcn_mfma_f32_16x16x32_bf16(a1, bh, acc[1][ct], 0,0,0);
        acc[1][ct] = __builtin_amdgcn_mfma_f32_16x16x32_bf16(a1, bl, acc[1][ct], 0,0,0);
      }
    }
  }
  float b1v[8], w2v[8];
  #pragma unroll
  for (int ct=0; ct<8; ct++){
    b1v[ct] = b1[ct*16 + lr];
    w2v[ct] = w2[ct*16 + lr];
  }
  const float bias2 = b2[0];
  #pragma unroll
  for (int strip=0; strip<2; strip++){
    #pragma unroll
    for (int i=0;i<4;i++){
      float p = 0.f;
      #pragma unroll
      for (int ct=0; ct<8; ct++){
        p += tanhf(acc[strip][ct][i] + b1v[ct]) * w2v[ct];
      }
      p += __shfl_xor(p, 1, 16);
      p += __shfl_xor(p, 2, 16);
      p += __shfl_xor(p, 4, 16);
      p += __shfl_xor(p, 8, 16);
      if (lr == 0){
        int rib = wave*32 + strip*16 + kg*4 + i;
        int R = rowBase + rib;
        if (R < N){
          float e = expf(p + bias2);
          sAex[rib] = e;
          atomicAdd(&sden[sBatch[rib]], e);
        }
      }
    }
  }
  __syncthreads();
  {
    const int cpair = tid & 63;
    const int rgrp  = tid >> 6;
    const unsigned* __restrict__ xu = (const unsigned*)xa;
    float p0 = 0.f, p1 = 0.f;
    int gcur = -1;
    for (int r = rgrp*32; r < rgrp*32 + 32; ++r){
      int R = rowBase + r;
      if (R >= N) break;
      int g = sBatch[r];
      if (g != gcur){
        if (gcur >= 0){
          atomicAdd(&pooled[gcur*128 + cpair*2],     p0);
          atomicAdd(&pooled[gcur*128 + cpair*2 + 1], p1);
        }
        p0 = 0.f; p1 = 0.f; gcur = g;
      }
      float e = sAex[r];
      unsigned u = xu[(size_t)R*64 + cpair];
      p0 = __builtin_fmaf(e, bflo(u), p0);
      p1 = __builtin_fmaf(e, bfhi(u), p1);
    }
    if (gcur >= 0){
      atomicAdd(&pooled[gcur*128 + cpair*2],     p0);
      atomicAdd(&pooled[gcur*128 + cpair*2 + 1], p1);
    }
  }
  if (tid < 8 && sden[tid] != 0.f) atomicAdd(&denom[tid], sden[tid]);
}

// ---------------- gather: 16 lanes per node, degree-sorted order ----------------
#define GFMA8(U, NJ) \
  a0=__builtin_fmaf(bflo(U.x),(NJ),a0); a1=__builtin_fmaf(bfhi(U.x),(NJ),a1); \
  a2=__builtin_fmaf(bflo(U.y),(NJ),a2); a3=__builtin_fmaf(bfhi(U.y),(NJ),a3); \
  a4=__builtin_fmaf(bflo(U.z),(NJ),a4); a5=__builtin_fmaf(bfhi(U.z),(NJ),a5); \
  a6=__builtin_fmaf(bflo(U.w),(NJ),a6); a7=__builtin_fmaf(bfhi(U.w),(NJ),a7);

__global__ __launch_bounds__(256) void gather_kernel(
    const unsigned short* __restrict__ hb, const float* __restrict__ dinv,
    const int* __restrict__ row_start, const int* __restrict__ csr_src,
    const int* __restrict__ perm,
    const float* __restrict__ bias, const float* __restrict__ bng, const float* __restrict__ bnb,
    const unsigned short* __restrict__ x1in, const unsigned short* __restrict__ x2in,
    unsigned short* __restrict__ out, int N, int mode)
{
  const int grp = (blockIdx.x * 256 + threadIdx.x) >> 4;
  const int sl  = threadIdx.x & 15;
  if (grp >= N) return;
  const int i = perm[grp];          // degree-sorted processing order
  const float di = dinv[i];
  const uint4* __restrict__ h4 = (const uint4*)hb;   // row = 16 uint4s

  float a0,a1,a2,a3,a4,a5,a6,a7;
  {
    uint4 u = h4[(size_t)i*16 + sl];
    float w0 = di*di;
    a0=bflo(u.x)*w0; a1=bfhi(u.x)*w0; a2=bflo(u.y)*w0; a3=bfhi(u.y)*w0;
    a4=bflo(u.z)*w0; a5=bfhi(u.z)*w0; a6=bflo(u.w)*w0; a7=bfhi(u.w)*w0;
  }
  int base = row_start[i];
  const int s1 = row_start[i+1];
  // full chunks of 16 edges, 4-deep load batches (round-7 proven shape)
  while (base + 16 <= s1){
    int sv = csr_src[base + sl];
    float nv = dinv[sv]*di;
    #pragma unroll
    for (int j=0; j<16; j+=4){
      int sj0 = __shfl(sv, j,   16);
      int sj1 = __shfl(sv, j+1, 16);
      int sj2 = __shfl(sv, j+2, 16);
      int sj3 = __shfl(sv, j+3, 16);
      float nj0 = __shfl(nv, j,   16);
      float nj1 = __shfl(nv, j+1, 16);
      float nj2 = __shfl(nv, j+2, 16);
      float nj3 = __shfl(nv, j+3, 16);
      uint4 u0 = h4[(size_t)sj0*16 + sl];
      uint4 u1 = h4[(size_t)sj1*16 + sl];
      uint4 u2 = h4[(size_t)sj2*16 + sl];
      uint4 u3 = h4[(size_t)sj3*16 + sl];
      GFMA8(u0, nj0)
      GFMA8(u1, nj1)
      GFMA8(u2, nj2)
      GFMA8(u3, nj3)
    }
    base += 16;
  }
  // tail: padded groups of 4 (inactive slots read lane-0's row with weight 0)
  const int rem = s1 - base;
  if (rem > 0){
    int sv = 0; float nv = 0.f;
    if (sl < rem){ sv = csr_src[base + sl]; nv = dinv[sv]*di; }
    for (int j0=0; j0<rem; j0+=4){
      uint4 u[4]; float njv[4];
      #pragma unroll
      for (int q=0;q<4;q++){
        const int j = j0 + q;
        const int jj = (j < rem) ? j : 0;
        int   sjq = __shfl(sv, jj, 16);
        float njq = __shfl(nv, jj, 16);
        if (j >= rem) njq = 0.f;
        u[q] = h4[(size_t)sjq*16 + sl];
        njv[q] = njq;
      }
      #pragma unroll
      for (int q=0;q<4;q++){ GFMA8(u[q], njv[q]) }
    }
  }
  const int f0 = sl*8;
  const float bsc = rsqrtf(1.0f + EPSV);
  float4 bi0 = *(const float4*)(bias + f0);
  float4 bi1 = *(const float4*)(bias + f0 + 4);
  float4 g0 = *(const float4*)(bng + f0);
  float4 g1 = *(const float4*)(bng + f0 + 4);
  float4 be0 = *(const float4*)(bnb + f0);
  float4 be1 = *(const float4*)(bnb + f0 + 4);
  float v[8];
  v[0] = fmaxf(0.f, (a0+bi0.x)*(g0.x*bsc) + be0.x);
  v[1] = fmaxf(0.f, (a1+bi0.y)*(g0.y*bsc) + be0.y);
  v[2] = fmaxf(0.f, (a2+bi0.z)*(g0.z*bsc) + be0.z);
  v[3] = fmaxf(0.f, (a3+bi0.w)*(g0.w*bsc) + be0.w);
  v[4] = fmaxf(0.f, (a4+bi1.x)*(g1.x*bsc) + be1.x);
  v[5] = fmaxf(0.f, (a5+bi1.y)*(g1.y*bsc) + be1.y);
  v[6] = fmaxf(0.f, (a6+bi1.z)*(g1.z*bsc) + be1.z);
  v[7] = fmaxf(0.f, (a7+bi1.w)*(g1.w*bsc) + be1.w);
  if (mode == 2){
    uint4 up = ((const uint4*)x1in)[(size_t)i*16 + sl];
    uint4 uq = ((const uint4*)x2in)[(size_t)i*16 + sl];
    v[0]+=bflo(up.x)+bflo(uq.x); v[1]+=bfhi(up.x)+bfhi(uq.x);
    v[2]+=bflo(up.y)+bflo(uq.y); v[3]+=bfhi(up.y)+bfhi(uq.y);
    v[4]+=bflo(up.z)+bflo(uq.z); v[5]+=bfhi(up.z)+bfhi(uq.z);
    v[6]+=bflo(up.w)+bflo(uq.w); v[7]+=bfhi(up.w)+bfhi(uq.w);
  }
  unsigned o[4];
  o[0]=pk2bf(v[0],v[1]); o[1]=pk2bf(v[2],v[3]); o[2]=pk2bf(v[4],v[5]); o[3]=pk2bf(v[6],v[7]);
  ((uint4*)out)[(size_t)i*16 + sl] = *(const uint4*)o;
}

// ---------------- classifier head (single block) ----------------
__global__ __launch_bounds__(256) void classifier_kernel(
    const float* __restrict__ pooled, const float* __restrict__ denom,
    const float* __restrict__ w1, const float* __restrict__ b1,
    const float* __restrict__ g1, const float* __restrict__ be1,
    const float* __restrict__ w2, const float* __restrict__ b2,
    const float* __restrict__ g2, const float* __restrict__ be2,
    const float* __restrict__ w3, const float* __restrict__ b3,
    float* __restrict__ outp)
{
  __shared__ float pl[8*128];
  __shared__ float h1[8*256];
  __shared__ float h2l[8*128];
  int t = threadIdx.x;
  for (int idx = t; idx < 1024; idx += 256){
    int g = idx >> 7;
    pl[idx] = pooled[idx] / denom[g];
  }
  __syncthreads();
  {
    float a0=0,a1=0,a2=0,a3=0,a4=0,a5=0,a6=0,a7=0;
    for (int k=0; k<128; k++){
      float w = w1[k*256 + t];
      a0 = __builtin_fmaf(pl[0*128+k], w, a0);
      a1 = __builtin_fmaf(pl[1*128+k], w, a1);
      a2 = __builtin_fmaf(pl[2*128+k], w, a2);
      a3 = __builtin_fmaf(pl[3*128+k], w, a3);
      a4 = __builtin_fmaf(pl[4*128+k], w, a4);
      a5 = __builtin_fmaf(pl[5*128+k], w, a5);
      a6 = __builtin_fmaf(pl[6*128+k], w, a6);
      a7 = __builtin_fmaf(pl[7*128+k], w, a7);
    }
    float s = g1[t]*rsqrtf(1.0f + EPSV);
    float bb = b1[t], tb = be1[t];
    h1[0*256+t] = fmaxf(0.f, (a0+bb)*s + tb);
    h1[1*256+t] = fmaxf(0.f, (a1+bb)*s + tb);
    h1[2*256+t] = fmaxf(0.f, (a2+bb)*s + tb);
    h1[3*256+t] = fmaxf(0.f, (a3+bb)*s + tb);
    h1[4*256+t] = fmaxf(0.f, (a4+bb)*s + tb);
    h1[5*256+t] = fmaxf(0.f, (a5+bb)*s + tb);
    h1[6*256+t] = fmaxf(0.f, (a6+bb)*s + tb);
    h1[7*256+t] = fmaxf(0.f, (a7+bb)*s + tb);
  }
  __syncthreads();
  if (t < 128){
    float a0=0,a1=0,a2=0,a3=0,a4=0,a5=0,a6=0,a7=0;
    for (int k=0; k<256; k++){
      float w = w2[k*128 + t];
      a0 = __builtin_fmaf(h1[0*256+k], w, a0);
      a1 = __builtin_fmaf(h1[1*256+k], w, a1);
      a2 = __builtin_fmaf(h1[2*256+k], w, a2);
      a3 = __builtin_fmaf(h1[3*256+k], w, a3);
      a4 = __builtin_fmaf(h1[4*256+k], w, a4);
      a5 = __builtin_fmaf(h1[5*256+k], w, a5);
      a6 = __builtin_fmaf(h1[6*256+k], w, a6);
      a7 = __builtin_fmaf(h1[7*256+k], w, a7);
    }
    float s = g2[t]*rsqrtf(1.0f + EPSV);
    float bb = b2[t], tb = be2[t];
    h2l[0*128+t] = fmaxf(0.f, (a0+bb)*s + tb);
    h2l[1*128+t] = fmaxf(0.f, (a1+bb)*s + tb);
    h2l[2*128+t] = fmaxf(0.f, (a2+bb)*s + tb);
    h2l[3*128+t] = fmaxf(0.f, (a3+bb)*s + tb);
    h2l[4*128+t] = fmaxf(0.f, (a4+bb)*s + tb);
    h2l[5*128+t] = fmaxf(0.f, (a5+bb)*s + tb);
    h2l[6*128+t] = fmaxf(0.f, (a6+bb)*s + tb);
    h2l[7*128+t] = fmaxf(0.f, (a7+bb)*s + tb);
  }
  __syncthreads();
  if (t < 40){
    int g = t/5, c = t%5;
    float s = 0.f;
    for (int k=0; k<128; k++) s = __builtin_fmaf(h2l[g*128+k], w3[k*5+c], s);
    outp[t] = s + b3[c];
  }
}

extern "C" void kernel_launch(void* const* d_in, const int* in_sizes, int n_in,
                              void* d_out, int out_size, void* d_ws, size_t ws_size,
                              hipStream_t stream)
{
  const float* cnn   = (const float*)d_in[0];
  const float* morph = (const float*)d_in[1];
  const int*   eidx  = (const int*)d_in[2];
  const int*   batch = (const int*)d_in[3];
  const float* g1w = (const float*)d_in[4];
  const float* g1b = (const float*)d_in[5];
  const float* g2w = (const float*)d_in[6];
  const float* g2b = (const float*)d_in[7];
  const float* g3w = (const float*)d_in[8];
  const float* g3b = (const float*)d_in[9];
  const float* bn1g=(const float*)d_in[10], *bn1b=(const float*)d_in[11];
  const float* bn2g=(const float*)d_in[12], *bn2b=(const float*)d_in[13];
  const float* bn3g=(const float*)d_in[14], *bn3b=(const float*)d_in[15];
  const float* aw1=(const float*)d_in[16], *ab1=(const float*)d_in[17];
  const float* aw2=(const float*)d_in[18], *ab2=(const float*)d_in[19];
  const float* cw1=(const float*)d_in[20], *cb1=(const float*)d_in[21];
  const float* c1g=(const float*)d_in[22], *c1b=(const float*)d_in[23];
  const float* cw2=(const float*)d_in[24], *cb2=(const float*)d_in[25];
  const float* c2g=(const float*)d_in[26], *c2b=(const float*)d_in[27];
  const float* cw3=(const float*)d_in[28], *cb3=(const float*)d_in[29];

  const int N = in_sizes[3];
  const int E = in_sizes[2] / 2;
  const int CNNW = in_sizes[0] / N;   // 768
  const int MOR  = in_sizes[1] / N;   // 6
  const int D = CNNW + MOR;           // 774
  const int Dpad1 = ((D + 63)/64)*64; // 832

  char* p = (char*)d_ws;
  auto alloc = [&](size_t bytes)->char* {
    char* r = p; p += (bytes + 255) & ~(size_t)255; return r;
  };
  unsigned short* hbuf = (unsigned short*)alloc((size_t)N*128*2);  // bf16 h
  unsigned short* x1   = (unsigned short*)alloc((size_t)N*128*2);  // bf16 x1 / x_out
  unsigned short* x2   = (unsigned short*)alloc((size_t)N*128*2);  // bf16 x2
  float* dinv  = (float*)alloc((size_t)N*4);
  char* zstart = p;
  int* deg      = (int*)alloc((size_t)N*4);
  float* denom  = (float*)alloc(8*4);
  float* pooled = (float*)alloc(8*128*4);
  int* dhist    = (int*)alloc(64*4);
  int* dcur     = (int*)alloc(64*4);
  size_t zbytes = (size_t)(p - zstart);
  int* row_start=(int*)alloc((size_t)(N+1)*4);
  int* cursor  = (int*)alloc((size_t)N*4);
  int* csr_src = (int*)alloc((size_t)E*4);
  int* perm    = (int*)alloc((size_t)N*4);
  int* bsums   = (int*)alloc(4096);
  unsigned short* w1T = (unsigned short*)alloc((size_t)128*Dpad1*2);
  unsigned short* w2T = (unsigned short*)alloc((size_t)128*128*2);
  unsigned short* w3T = (unsigned short*)alloc((size_t)128*128*2);
  unsigned short* aw1hiT = (unsigned short*)alloc((size_t)128*128*2);
  unsigned short* aw1loT = (unsigned short*)alloc((size_t)128*128*2);

  hipMemsetAsync(zstart, 0, zbytes, stream);

  const int* srcp = eidx;
  const int* dstp = eidx + E;

  int gE = (E + 255)/256;
  int gN = (N + 255)/256;
  int B  = (N + 1023)/1024;
  int gMfma = (N + 127)/128;
  int gGat  = (N + 15)/16;

  // CSR build
  hist_kernel<<<dim3(gE), dim3(256), 0, stream>>>(dstp, deg, E);
  scan_partial<<<dim3(B), dim3(256), 0, stream>>>(deg, bsums, N);
  scan_bsums<<<dim3(1), dim3(64), 0, stream>>>(bsums, row_start, B, N, E);
  scan_final<<<dim3(B), dim3(256), 0, stream>>>(deg, bsums, row_start, cursor, dinv, N);
  scatter_kernel<<<dim3(gE), dim3(256), 0, stream>>>(srcp, dstp, cursor, csr_src, E);

  // degree-sorted node order
  deghist_kernel<<<dim3(gN), dim3(256), 0, stream>>>(deg, dhist, N);
  degscan_kernel<<<dim3(1), dim3(64), 0, stream>>>(dhist, dcur);
  degscatter_kernel<<<dim3(gN), dim3(256), 0, stream>>>(deg, dcur, perm, N);

  // weight pre-convert
  wsplit_kernel<<<dim3((Dpad1+255)/256, 128), dim3(256), 0, stream>>>(g1w, w1T, D, Dpad1);
  wsplit_all<<<dim3(1, 128, 3), dim3(128), 0, stream>>>(g2w, g3w, aw1, w2T, w3T, aw1hiT, aw1loT);

  // GCN layer 1 (concat fp32 input)
  gemm_mfma_kernel<<<dim3(gMfma), dim3(256), 0, stream>>>(cnn, morph, w1T, hbuf, N, CNNW, MOR, Dpad1);
  gather_kernel<<<dim3(gGat), dim3(256), 0, stream>>>(hbuf, dinv, row_start, csr_src, perm,
      g1b, bn1g, bn1b, (const unsigned short*)nullptr, (const unsigned short*)nullptr, x1, N, 0);
  // GCN layer 2 (bf16 input)
  gemm_bf16_kernel<<<dim3(gMfma), dim3(256), 0, stream>>>(x1, w2T, hbuf, N);
  gather_kernel<<<dim3(gGat), dim3(256), 0, stream>>>(hbuf, dinv, row_start, csr_src, perm,
      g2b, bn2g, bn2b, (const unsigned short*)nullptr, (const unsigned short*)nullptr, x2, N, 0);
  // GCN layer 3 -> x_out = x1+x2+x3 into x1
  gemm_bf16_kernel<<<dim3(gMfma), dim3(256), 0, stream>>>(x2, w3T, hbuf, N);
  gather_kernel<<<dim3(gGat), dim3(256), 0, stream>>>(hbuf, dinv, row_start, csr_src, perm,
      g3b, bn3g, bn3b, x1, x2, x1, N, 2);

  // attention + softmax-denominator + pooling (fused)
  att_pool_kernel<<<dim3(gMfma), dim3(256), 0, stream>>>(x1, aw1hiT, aw1loT,
      ab1, aw2, ab2, batch, pooled, denom, N);

  classifier_kernel<<<dim3(1), dim3(256), 0, stream>>>(pooled, denom,
      cw1, cb1, c1g, c1b, cw2, cb2, c2g, c2b, cw3, cb3, (float*)d_out);
}

// Round 10
// 678.322 us; speedup vs baseline: 1.4692x; 1.4692x over previous
//
#include <hip/hip_runtime.h>
#include <hip/hip_bf16.h>

#define EPSV 1e-5f

typedef short short8v __attribute__((ext_vector_type(8)));
typedef float f32x4 __attribute__((ext_vector_type(4)));

// ---------- bf16 helpers ----------
__device__ __forceinline__ unsigned short f2bf(float f){ // RNE
  unsigned u = __float_as_uint(f);
  unsigned r = u + 0x7fffu + ((u >> 16) & 1u);
  return (unsigned short)(r >> 16);
}
__device__ __forceinline__ unsigned pk2bf(float x, float y){
  return (unsigned)f2bf(x) | ((unsigned)f2bf(y) << 16);
}
__device__ __forceinline__ float bf2f(unsigned short s){
  return __uint_as_float(((unsigned)s) << 16);
}
__device__ __forceinline__ float bflo(unsigned u){ return __uint_as_float(u << 16); }
__device__ __forceinline__ float bfhi(unsigned u){ return __uint_as_float(u & 0xffff0000u); }

// ---------------- degree histogram ----------------
__global__ void hist_kernel(const int* __restrict__ dst, int* __restrict__ deg, int E){
  int i = blockIdx.x*256 + threadIdx.x;
  if (i < E) atomicAdd(&deg[dst[i]], 1);
}

// ---------------- scan ----------------
__global__ void scan_partial(const int* __restrict__ deg, int* __restrict__ bsums, int N){
  __shared__ int sd[256];
  int t = threadIdx.x;
  int base = blockIdx.x*1024 + t*4;
  int s = 0;
  if (base+0 < N) s += deg[base+0];
  if (base+1 < N) s += deg[base+1];
  if (base+2 < N) s += deg[base+2];
  if (base+3 < N) s += deg[base+3];
  sd[t]=s; __syncthreads();
  for (int off=128; off>0; off>>=1){
    if (t<off) sd[t]+=sd[t+off];
    __syncthreads();
  }
  if (t==0) bsums[blockIdx.x]=sd[0];
}

__global__ void scan_bsums(int* bsums, int* row_start, int B, int N, int E){
  if (threadIdx.x==0 && blockIdx.x==0){
    int run=0;
    for (int b=0;b<B;b++){ int v=bsums[b]; bsums[b]=run; run+=v; }
    row_start[N]=E;
  }
}

// scan_final + dinv fused
__global__ void scan_final(const int* __restrict__ deg, const int* __restrict__ bsums,
                           int* __restrict__ row_start, int* __restrict__ cursor,
                           float* __restrict__ dinv, int N){
  __shared__ int sd[256];
  int t=threadIdx.x, b=blockIdx.x;
  int base=b*1024+t*4;
  int v0=0,v1=0,v2=0,v3=0;
  if (base+0<N) v0=deg[base+0];
  if (base+1<N) v1=deg[base+1];
  if (base+2<N) v2=deg[base+2];
  if (base+3<N) v3=deg[base+3];
  int s=v0+v1+v2+v3;
  sd[t]=s; __syncthreads();
  for (int off=1; off<256; off<<=1){
    int x = (t>=off)?sd[t-off]:0;
    __syncthreads();
    sd[t]+=x;
    __syncthreads();
  }
  int excl = sd[t]-s + bsums[b];
  int e0=excl, e1=excl+v0, e2=e1+v1, e3=e2+v2;
  if (base+0<N){ row_start[base+0]=e0; cursor[base+0]=e0; dinv[base+0]=rsqrtf((float)v0+1.0f); }
  if (base+1<N){ row_start[base+1]=e1; cursor[base+1]=e1; dinv[base+1]=rsqrtf((float)v1+1.0f); }
  if (base+2<N){ row_start[base+2]=e2; cursor[base+2]=e2; dinv[base+2]=rsqrtf((float)v2+1.0f); }
  if (base+3<N){ row_start[base+3]=e3; cursor[base+3]=e3; dinv[base+3]=rsqrtf((float)v3+1.0f); }
}

// scatter + edge weight precompute: csr_ew[pos] = {src, bits(dinv[d]*dinv[s])}
__global__ void scatter_kernel(const int* __restrict__ src, const int* __restrict__ dst,
                               int* __restrict__ cursor, const float* __restrict__ dinv,
                               int2* __restrict__ csr_ew, int E){
  int i = blockIdx.x*256 + threadIdx.x;
  if (i < E){
    int s = src[i];
    int d = dst[i];
    int pos = atomicAdd(&cursor[d], 1);
    float w = dinv[d]*dinv[s];
    csr_ew[pos] = make_int2(s, __float_as_int(w));
  }
}

// ---------------- W pre-convert: W[D x 128] fp32 -> WT [128 x Dpad] bf16 ----------------
__global__ void wsplit_kernel(const float* __restrict__ W, unsigned short* __restrict__ WT,
                              int D, int Dpad){
  int k = blockIdx.x*256 + threadIdx.x;
  int c = blockIdx.y;
  if (k >= Dpad) return;
  float v = (k < D) ? W[(size_t)k*128 + c] : 0.f;
  WT[(size_t)c*Dpad + k] = f2bf(v);
}

// fused small-weight convert: z=0 -> w2T, z=1 -> w3T, z=2 -> aw1 hi/lo
__global__ void wsplit_all(const float* __restrict__ W2, const float* __restrict__ W3,
                           const float* __restrict__ WA,
                           unsigned short* __restrict__ w2T, unsigned short* __restrict__ w3T,
                           unsigned short* __restrict__ aT_hi, unsigned short* __restrict__ aT_lo){
  int k = threadIdx.x;
  int c = blockIdx.y;
  int z = blockIdx.z;
  if (z == 0){
    w2T[c*128 + k] = f2bf(W2[(size_t)k*128 + c]);
  } else if (z == 1){
    w3T[c*128 + k] = f2bf(W3[(size_t)k*128 + c]);
  } else {
    float v = WA[(size_t)k*128 + c];
    unsigned short h = f2bf(v);
    aT_hi[c*128 + k] = h;
    aT_lo[c*128 + k] = f2bf(v - bf2f(h));
  }
}

// ---------------- GEMM1: A fp32 concat -> bf16 out, register prefetch ----------------
#define LOADA(KC) { \
  const int gk0 = (KC) + akseg; \
  if ((Rst < N) && (gk0 + 32 <= Da)){ \
    const float4* p4 = (const float4*)(xa + (size_t)Rst*Da + gk0); \
    pa0=p4[0]; pa1=p4[1]; pa2=p4[2]; pa3=p4[3]; pa4=p4[4]; pa5=p4[5]; pa6=p4[6]; pa7=p4[7]; \
  } else { \
    float tmp[32]; \
    _Pragma("unroll") \
    for (int q=0;q<32;q++){ \
      int gk = gk0 + q; float x = 0.f; \
      if (Rst < N){ \
        if (gk < Da) x = xa[(size_t)Rst*Da + gk]; \
        else if (gk < D) x = xb[(size_t)Rst*Db + (gk - Da)]; \
      } \
      tmp[q]=x; } \
    pa0=*(float4*)&tmp[0];  pa1=*(float4*)&tmp[4];  pa2=*(float4*)&tmp[8];  pa3=*(float4*)&tmp[12]; \
    pa4=*(float4*)&tmp[16]; pa5=*(float4*)&tmp[20]; pa6=*(float4*)&tmp[24]; pa7=*(float4*)&tmp[28]; \
  } }

#define LOADW(KC) { \
  const unsigned short* ph = wrowp + (KC); \
  pw0=*(const uint4*)(ph); pw1=*(const uint4*)(ph+8); pw2=*(const uint4*)(ph+16); pw3=*(const uint4*)(ph+24); }

__global__ __launch_bounds__(256, 3) void gemm_mfma_kernel(
    const float* __restrict__ xa, const float* __restrict__ xb,
    const unsigned short* __restrict__ WT,
    unsigned short* __restrict__ outb, int N, int Da, int Db, int Dpad)
{
  __shared__ unsigned short Abf[128*64];
  __shared__ unsigned short Bbf[128*64];

  const int tid  = threadIdx.x;
  const int lane = tid & 63;
  const int wave = tid >> 6;
  const int lr   = lane & 15;
  const int kg   = lane >> 4;
  const int rowBase = blockIdx.x * 128;
  const int D = Da + Db;

  f32x4 acc[2][8];
  #pragma unroll
  for (int s=0;s<2;s++)
    #pragma unroll
    for (int c=0;c<8;c++){ acc[s][c][0]=0.f; acc[s][c][1]=0.f; acc[s][c][2]=0.f; acc[s][c][3]=0.f; }

  const int arow = tid >> 1;
  const int akseg = (tid & 1) * 32;
  const int Rst = rowBase + arow;
  const int abase = arow*128 + akseg*2;
  const int aswz  = (arow & 7) << 4;
  const unsigned short* wrowp = WT + (size_t)arow*Dpad + akseg;

  float4 pa0,pa1,pa2,pa3,pa4,pa5,pa6,pa7;
  uint4  pw0,pw1,pw2,pw3;

  LOADA(0)
  LOADW(0)

  for (int kc = 0; kc < Dpad; kc += 64){
    __syncthreads();
    {
      unsigned u[4];
      u[0]=pk2bf(pa0.x,pa0.y); u[1]=pk2bf(pa0.z,pa0.w); u[2]=pk2bf(pa1.x,pa1.y); u[3]=pk2bf(pa1.z,pa1.w);
      *(uint4*)((char*)Abf + ((abase+ 0)^aswz)) = *(const uint4*)u;
      u[0]=pk2bf(pa2.x,pa2.y); u[1]=pk2bf(pa2.z,pa2.w); u[2]=pk2bf(pa3.x,pa3.y); u[3]=pk2bf(pa3.z,pa3.w);
      *(uint4*)((char*)Abf + ((abase+16)^aswz)) = *(const uint4*)u;
      u[0]=pk2bf(pa4.x,pa4.y); u[1]=pk2bf(pa4.z,pa4.w); u[2]=pk2bf(pa5.x,pa5.y); u[3]=pk2bf(pa5.z,pa5.w);
      *(uint4*)((char*)Abf + ((abase+32)^aswz)) = *(const uint4*)u;
      u[0]=pk2bf(pa6.x,pa6.y); u[1]=pk2bf(pa6.z,pa6.w); u[2]=pk2bf(pa7.x,pa7.y); u[3]=pk2bf(pa7.z,pa7.w);
      *(uint4*)((char*)Abf + ((abase+48)^aswz)) = *(const uint4*)u;
      *(uint4*)((char*)Bbf + ((abase+ 0)^aswz)) = pw0;
      *(uint4*)((char*)Bbf + ((abase+16)^aswz)) = pw1;
      *(uint4*)((char*)Bbf + ((abase+32)^aswz)) = pw2;
      *(uint4*)((char*)Bbf + ((abase+48)^aswz)) = pw3;
    }
    __syncthreads();
    const int kn = kc + 64;
    if (kn < Dpad){
      LOADA(kn)
      LOADW(kn)
    }
    #pragma unroll
    for (int ks=0; ks<2; ks++){
      const int kb = ks*64 + kg*16;
      const int r0 = wave*32 + lr;
      const int r1 = r0 + 16;
      const int offA0 = (r0*128 + kb) ^ ((r0&7)<<4);
      const int offA1 = (r1*128 + kb) ^ ((r1&7)<<4);
      short8v a0 = *(const short8v*)((const char*)Abf + offA0);
      short8v a1 = *(const short8v*)((const char*)Abf + offA1);
      #pragma unroll
      for (int ct=0; ct<8; ct++){
        const int c = ct*16 + lr;
        const int offB = (c*128 + kb) ^ ((c&7)<<4);
        short8v b = *(const short8v*)((const char*)Bbf + offB);
        acc[0][ct] = __builtin_amdgcn_mfma_f32_16x16x32_bf16(a0, b, acc[0][ct], 0,0,0);
        acc[1][ct] = __builtin_amdgcn_mfma_f32_16x16x32_bf16(a1, b, acc[1][ct], 0,0,0);
      }
    }
  }
  const int wrow = rowBase + wave*32;
  #pragma unroll
  for (int strip=0; strip<2; strip++){
    #pragma unroll
    for (int ct=0; ct<8; ct++){
      #pragma unroll
      for (int i=0;i<4;i++){
        int R = wrow + strip*16 + kg*4 + i;
        int C = ct*16 + lr;
        if (R < N) outb[(size_t)R*128 + C] = f2bf(acc[strip][ct][i]);
      }
    }
  }
}

// ---------------- GEMM2/3: A bf16 [N x 128] -> bf16 out ----------------
__global__ __launch_bounds__(256, 3) void gemm_bf16_kernel(
    const unsigned short* __restrict__ xa,
    const unsigned short* __restrict__ WT,
    unsigned short* __restrict__ outb, int N)
{
  __shared__ unsigned short Abf[128*64];
  __shared__ unsigned short Bbf[128*64];

  const int tid  = threadIdx.x;
  const int lane = tid & 63;
  const int wave = tid >> 6;
  const int lr   = lane & 15;
  const int kg   = lane >> 4;
  const int rowBase = blockIdx.x * 128;

  f32x4 acc[2][8];
  #pragma unroll
  for (int s=0;s<2;s++)
    #pragma unroll
    for (int c=0;c<8;c++){ acc[s][c][0]=0.f; acc[s][c][1]=0.f; acc[s][c][2]=0.f; acc[s][c][3]=0.f; }

  const int arow = tid >> 1;
  const int akseg = (tid & 1) * 32;
  const int Rst = rowBase + arow;
  const int abase = arow*128 + akseg*2;
  const int aswz  = (arow & 7) << 4;
  const unsigned short* arp = xa + (size_t)Rst*128 + akseg;
  const unsigned short* wrp = WT + (size_t)arow*128 + akseg;

  uint4 pa0,pa1,pa2,pa3, pw0,pw1,pw2,pw3;
  uint4 z4; z4.x=0; z4.y=0; z4.z=0; z4.w=0;
  if (Rst < N){ pa0=*(const uint4*)(arp); pa1=*(const uint4*)(arp+8); pa2=*(const uint4*)(arp+16); pa3=*(const uint4*)(arp+24); }
  else { pa0=z4; pa1=z4; pa2=z4; pa3=z4; }
  pw0=*(const uint4*)(wrp); pw1=*(const uint4*)(wrp+8); pw2=*(const uint4*)(wrp+16); pw3=*(const uint4*)(wrp+24);

  #pragma unroll
  for (int kc = 0; kc < 128; kc += 64){
    __syncthreads();
    *(uint4*)((char*)Abf + ((abase+ 0)^aswz)) = pa0;
    *(uint4*)((char*)Abf + ((abase+16)^aswz)) = pa1;
    *(uint4*)((char*)Abf + ((abase+32)^aswz)) = pa2;
    *(uint4*)((char*)Abf + ((abase+48)^aswz)) = pa3;
    *(uint4*)((char*)Bbf + ((abase+ 0)^aswz)) = pw0;
    *(uint4*)((char*)Bbf + ((abase+16)^aswz)) = pw1;
    *(uint4*)((char*)Bbf + ((abase+32)^aswz)) = pw2;
    *(uint4*)((char*)Bbf + ((abase+48)^aswz)) = pw3;
    __syncthreads();
    if (kc == 0){
      if (Rst < N){ pa0=*(const uint4*)(arp+64); pa1=*(const uint4*)(arp+72); pa2=*(const uint4*)(arp+80); pa3=*(const uint4*)(arp+88); }
      pw0=*(const uint4*)(wrp+64); pw1=*(const uint4*)(wrp+72); pw2=*(const uint4*)(wrp+80); pw3=*(const uint4*)(wrp+88);
    }
    #pragma unroll
    for (int ks=0; ks<2; ks++){
      const int kb = ks*64 + kg*16;
      const int r0 = wave*32 + lr;
      const int r1 = r0 + 16;
      const int offA0 = (r0*128 + kb) ^ ((r0&7)<<4);
      const int offA1 = (r1*128 + kb) ^ ((r1&7)<<4);
      short8v a0 = *(const short8v*)((const char*)Abf + offA0);
      short8v a1 = *(const short8v*)((const char*)Abf + offA1);
      #pragma unroll
      for (int ct=0; ct<8; ct++){
        const int c = ct*16 + lr;
        const int offB = (c*128 + kb) ^ ((c&7)<<4);
        short8v b = *(const short8v*)((const char*)Bbf + offB);
        acc[0][ct] = __builtin_amdgcn_mfma_f32_16x16x32_bf16(a0, b, acc[0][ct], 0,0,0);
        acc[1][ct] = __builtin_amdgcn_mfma_f32_16x16x32_bf16(a1, b, acc[1][ct], 0,0,0);
      }
    }
  }
  const int wrow = rowBase + wave*32;
  #pragma unroll
  for (int strip=0; strip<2; strip++){
    #pragma unroll
    for (int ct=0; ct<8; ct++){
      #pragma unroll
      for (int i=0;i<4;i++){
        int R = wrow + strip*16 + kg*4 + i;
        int C = ct*16 + lr;
        if (R < N) outb[(size_t)R*128 + C] = f2bf(acc[strip][ct][i]);
      }
    }
  }
}

// ---------------- attention + pooling fused ----------------
__global__ __launch_bounds__(256) void att_pool_kernel(
    const unsigned short* __restrict__ xa,
    const unsigned short* __restrict__ WhiT, const unsigned short* __restrict__ WloT,
    const float* __restrict__ b1, const float* __restrict__ w2, const float* __restrict__ b2,
    const int* __restrict__ batch,
    float* __restrict__ pooled, float* __restrict__ denom, int N)
{
  __shared__ unsigned short Abf[128*64];
  __shared__ unsigned short Bhi[128*64];
  __shared__ unsigned short Blo[128*64];
  __shared__ float sden[8];
  __shared__ float sAex[128];
  __shared__ int   sBatch[128];

  const int tid  = threadIdx.x;
  const int lane = tid & 63;
  const int wave = tid >> 6;
  const int lr   = lane & 15;
  const int kg   = lane >> 4;
  const int rowBase = blockIdx.x * 128;

  if (tid < 8) sden[tid] = 0.f;
  if (tid < 128){
    int R = rowBase + tid;
    sBatch[tid] = (R < N) ? batch[R] : -1;
  }

  f32x4 acc[2][8];
  #pragma unroll
  for (int s=0;s<2;s++)
    #pragma unroll
    for (int c=0;c<8;c++){ acc[s][c][0]=0.f; acc[s][c][1]=0.f; acc[s][c][2]=0.f; acc[s][c][3]=0.f; }

  const int arow = tid >> 1;
  const int akseg = (tid & 1) * 32;
  const int Rst = rowBase + arow;
  const int abase = arow*128 + akseg*2;
  const int aswz  = (arow & 7) << 4;
  const unsigned short* arp = xa + (size_t)Rst*128 + akseg;

  #pragma unroll
  for (int kc = 0; kc < 128; kc += 64){
    __syncthreads();
    {
      uint4 z4; z4.x=0; z4.y=0; z4.z=0; z4.w=0;
      uint4 a0=z4,a1=z4,a2=z4,a3=z4;
      if (Rst < N){
        a0=*(const uint4*)(arp+kc); a1=*(const uint4*)(arp+kc+8);
        a2=*(const uint4*)(arp+kc+16); a3=*(const uint4*)(arp+kc+24);
      }
      *(uint4*)((char*)Abf + ((abase+ 0)^aswz)) = a0;
      *(uint4*)((char*)Abf + ((abase+16)^aswz)) = a1;
      *(uint4*)((char*)Abf + ((abase+32)^aswz)) = a2;
      *(uint4*)((char*)Abf + ((abase+48)^aswz)) = a3;
      const unsigned short* ph = WhiT + (size_t)arow*128 + kc + akseg;
      const unsigned short* pl = WloT + (size_t)arow*128 + kc + akseg;
      *(uint4*)((char*)Bhi + ((abase+ 0)^aswz)) = *(const uint4*)(ph);
      *(uint4*)((char*)Bhi + ((abase+16)^aswz)) = *(const uint4*)(ph+8);
      *(uint4*)((char*)Bhi + ((abase+32)^aswz)) = *(const uint4*)(ph+16);
      *(uint4*)((char*)Bhi + ((abase+48)^aswz)) = *(const uint4*)(ph+24);
      *(uint4*)((char*)Blo + ((abase+ 0)^aswz)) = *(const uint4*)(pl);
      *(uint4*)((char*)Blo + ((abase+16)^aswz)) = *(const uint4*)(pl+8);
      *(uint4*)((char*)Blo + ((abase+32)^aswz)) = *(const uint4*)(pl+16);
      *(uint4*)((char*)Blo + ((abase+48)^aswz)) = *(const uint4*)(pl+24);
    }
    __syncthreads();
    #pragma unroll
    for (int ks=0; ks<2; ks++){
      const int kb = ks*64 + kg*16;
      const int r0 = wave*32 + lr;
      const int r1 = r0 + 16;
      const int offA0 = (r0*128 + kb) ^ ((r0&7)<<4);
      const int offA1 = (r1*128 + kb) ^ ((r1&7)<<4);
      short8v a0 = *(const short8v*)((const char*)Abf + offA0);
      short8v a1 = *(const short8v*)((const char*)Abf + offA1);
      #pragma unroll
      for (int ct=0; ct<8; ct++){
        const int c = ct*16 + lr;
        const int offB = (c*128 + kb) ^ ((c&7)<<4);
        short8v bh = *(const short8v*)((const char*)Bhi + offB);
        short8v bl = *(const short8v*)((const char*)Blo + offB);
        acc[0][ct] = __builtin_amdgcn_mfma_f32_16x16x32_bf16(a0, bh, acc[0][ct], 0,0,0);
        acc[0][ct] = __builtin_amdgcn_mfma_f32_16x16x32_bf16(a0, bl, acc[0][ct], 0,0,0);
        acc[1][ct] = __builtin_amdgcn_mfma_f32_16x16x32_bf16(a1, bh, acc[1][ct], 0,0,0);
        acc[1][ct] = __builtin_amdgcn_mfma_f32_16x16x32_bf16(a1, bl, acc[1][ct], 0,0,0);
      }
    }
  }
  float b1v[8], w2v[8];
  #pragma unroll
  for (int ct=0; ct<8; ct++){
    b1v[ct] = b1[ct*16 + lr];
    w2v[ct] = w2[ct*16 + lr];
  }
  const float bias2 = b2[0];
  #pragma unroll
  for (int strip=0; strip<2; strip++){
    #pragma unroll
    for (int i=0;i<4;i++){
      float p = 0.f;
      #pragma unroll
      for (int ct=0; ct<8; ct++){
        p += tanhf(acc[strip][ct][i] + b1v[ct]) * w2v[ct];
      }
      p += __shfl_xor(p, 1, 16);
      p += __shfl_xor(p, 2, 16);
      p += __shfl_xor(p, 4, 16);
      p += __shfl_xor(p, 8, 16);
      if (lr == 0){
        int rib = wave*32 + strip*16 + kg*4 + i;
        int R = rowBase + rib;
        if (R < N){
          float e = expf(p + bias2);
          sAex[rib] = e;
          atomicAdd(&sden[sBatch[rib]], e);
        }
      }
    }
  }
  __syncthreads();
  {
    const int cpair = tid & 63;
    const int rgrp  = tid >> 6;
    const unsigned* __restrict__ xu = (const unsigned*)xa;
    float p0 = 0.f, p1 = 0.f;
    int gcur = -1;
    for (int r = rgrp*32; r < rgrp*32 + 32; ++r){
      int R = rowBase + r;
      if (R >= N) break;
      int g = sBatch[r];
      if (g != gcur){
        if (gcur >= 0){
          atomicAdd(&pooled[gcur*128 + cpair*2],     p0);
          atomicAdd(&pooled[gcur*128 + cpair*2 + 1], p1);
        }
        p0 = 0.f; p1 = 0.f; gcur = g;
      }
      float e = sAex[r];
      unsigned u = xu[(size_t)R*64 + cpair];
      p0 = __builtin_fmaf(e, bflo(u), p0);
      p1 = __builtin_fmaf(e, bfhi(u), p1);
    }
    if (gcur >= 0){
      atomicAdd(&pooled[gcur*128 + cpair*2],     p0);
      atomicAdd(&pooled[gcur*128 + cpair*2 + 1], p1);
    }
  }
  if (tid < 8 && sden[tid] != 0.f) atomicAdd(&denom[tid], sden[tid]);
}

// ---------------- gather: 16 lanes per node, edge weights precomputed ----------------
#define GFMA8(U, NJ) \
  a0=__builtin_fmaf(bflo(U.x),(NJ),a0); a1=__builtin_fmaf(bfhi(U.x),(NJ),a1); \
  a2=__builtin_fmaf(bflo(U.y),(NJ),a2); a3=__builtin_fmaf(bfhi(U.y),(NJ),a3); \
  a4=__builtin_fmaf(bflo(U.z),(NJ),a4); a5=__builtin_fmaf(bfhi(U.z),(NJ),a5); \
  a6=__builtin_fmaf(bflo(U.w),(NJ),a6); a7=__builtin_fmaf(bfhi(U.w),(NJ),a7);

__global__ __launch_bounds__(256) void gather_kernel(
    const unsigned short* __restrict__ hb, const float* __restrict__ dinv,
    const int* __restrict__ row_start, const int2* __restrict__ csr_ew,
    const float* __restrict__ bias, const float* __restrict__ bng, const float* __restrict__ bnb,
    const unsigned short* __restrict__ x1in, const unsigned short* __restrict__ x2in,
    unsigned short* __restrict__ out, int N, int mode)
{
  const int grp = (blockIdx.x * 256 + threadIdx.x) >> 4;
  const int sl  = threadIdx.x & 15;
  if (grp >= N) return;
  const int i = grp;
  const float di = dinv[i];
  const uint4* __restrict__ h4 = (const uint4*)hb;   // row = 16 uint4s

  float a0,a1,a2,a3,a4,a5,a6,a7;
  {
    uint4 u = h4[(size_t)i*16 + sl];
    float w0 = di*di;
    a0=bflo(u.x)*w0; a1=bfhi(u.x)*w0; a2=bflo(u.y)*w0; a3=bfhi(u.y)*w0;
    a4=bflo(u.z)*w0; a5=bfhi(u.z)*w0; a6=bflo(u.w)*w0; a7=bfhi(u.w)*w0;
  }
  int base = row_start[i];
  const int s1 = row_start[i+1];
  // full chunks of 16 edges, 4-deep load batches; weight comes with the edge
  while (base + 16 <= s1){
    int2 ew = csr_ew[base + sl];
    int sv = ew.x;
    float nv = __int_as_float(ew.y);
    #pragma unroll
    for (int j=0; j<16; j+=4){
      int sj0 = __shfl(sv, j,   16);
      int sj1 = __shfl(sv, j+1, 16);
      int sj2 = __shfl(sv, j+2, 16);
      int sj3 = __shfl(sv, j+3, 16);
      float nj0 = __shfl(nv, j,   16);
      float nj1 = __shfl(nv, j+1, 16);
      float nj2 = __shfl(nv, j+2, 16);
      float nj3 = __shfl(nv, j+3, 16);
      uint4 u0 = h4[(size_t)sj0*16 + sl];
      uint4 u1 = h4[(size_t)sj1*16 + sl];
      uint4 u2 = h4[(size_t)sj2*16 + sl];
      uint4 u3 = h4[(size_t)sj3*16 + sl];
      GFMA8(u0, nj0)
      GFMA8(u1, nj1)
      GFMA8(u2, nj2)
      GFMA8(u3, nj3)
    }
    base += 16;
  }
  // tail: padded groups of 4 (inactive slots read lane-0's row with weight 0)
  const int rem = s1 - base;
  if (rem > 0){
    int sv = 0; float nv = 0.f;
    if (sl < rem){
      int2 ew = csr_ew[base + sl];
      sv = ew.x;
      nv = __int_as_float(ew.y);
    }
    for (int j0=0; j0<rem; j0+=4){
      uint4 u[4]; float njv[4];
      #pragma unroll
      for (int q=0;q<4;q++){
        const int j = j0 + q;
        const int jj = (j < rem) ? j : 0;
        int   sjq = __shfl(sv, jj, 16);
        float njq = __shfl(nv, jj, 16);
        if (j >= rem) njq = 0.f;
        u[q] = h4[(size_t)sjq*16 + sl];
        njv[q] = njq;
      }
      #pragma unroll
      for (int q=0;q<4;q++){ GFMA8(u[q], njv[q]) }
    }
  }
  const int f0 = sl*8;
  const float bsc = rsqrtf(1.0f + EPSV);
  float4 bi0 = *(const float4*)(bias + f0);
  float4 bi1 = *(const float4*)(bias + f0 + 4);
  float4 g0 = *(const float4*)(bng + f0);
  float4 g1 = *(const float4*)(bng + f0 + 4);
  float4 be0 = *(const float4*)(bnb + f0);
  float4 be1 = *(const float4*)(bnb + f0 + 4);
  float v[8];
  v[0] = fmaxf(0.f, (a0+bi0.x)*(g0.x*bsc) + be0.x);
  v[1] = fmaxf(0.f, (a1+bi0.y)*(g0.y*bsc) + be0.y);
  v[2] = fmaxf(0.f, (a2+bi0.z)*(g0.z*bsc) + be0.z);
  v[3] = fmaxf(0.f, (a3+bi0.w)*(g0.w*bsc) + be0.w);
  v[4] = fmaxf(0.f, (a4+bi1.x)*(g1.x*bsc) + be1.x);
  v[5] = fmaxf(0.f, (a5+bi1.y)*(g1.y*bsc) + be1.y);
  v[6] = fmaxf(0.f, (a6+bi1.z)*(g1.z*bsc) + be1.z);
  v[7] = fmaxf(0.f, (a7+bi1.w)*(g1.w*bsc) + be1.w);
  if (mode == 2){
    uint4 up = ((const uint4*)x1in)[(size_t)i*16 + sl];
    uint4 uq = ((const uint4*)x2in)[(size_t)i*16 + sl];
    v[0]+=bflo(up.x)+bflo(uq.x); v[1]+=bfhi(up.x)+bfhi(uq.x);
    v[2]+=bflo(up.y)+bflo(uq.y); v[3]+=bfhi(up.y)+bfhi(uq.y);
    v[4]+=bflo(up.z)+bflo(uq.z); v[5]+=bfhi(up.z)+bfhi(uq.z);
    v[6]+=bflo(up.w)+bflo(uq.w); v[7]+=bfhi(up.w)+bfhi(uq.w);
  }
  unsigned o[4];
  o[0]=pk2bf(v[0],v[1]); o[1]=pk2bf(v[2],v[3]); o[2]=pk2bf(v[4],v[5]); o[3]=pk2bf(v[6],v[7]);
  ((uint4*)out)[(size_t)i*16 + sl] = *(const uint4*)o;
}

// ---------------- classifier head (single block) ----------------
__global__ __launch_bounds__(256) void classifier_kernel(
    const float* __restrict__ pooled, const float* __restrict__ denom,
    const float* __restrict__ w1, const float* __restrict__ b1,
    const float* __restrict__ g1, const float* __restrict__ be1,
    const float* __restrict__ w2, const float* __restrict__ b2,
    const float* __restrict__ g2, const float* __restrict__ be2,
    const float* __restrict__ w3, const float* __restrict__ b3,
    float* __restrict__ outp)
{
  __shared__ float pl[8*128];
  __shared__ float h1[8*256];
  __shared__ float h2l[8*128];
  int t = threadIdx.x;
  for (int idx = t; idx < 1024; idx += 256){
    int g = idx >> 7;
    pl[idx] = pooled[idx] / denom[g];
  }
  __syncthreads();
  {
    float a0=0,a1=0,a2=0,a3=0,a4=0,a5=0,a6=0,a7=0;
    for (int k=0; k<128; k++){
      float w = w1[k*256 + t];
      a0 = __builtin_fmaf(pl[0*128+k], w, a0);
      a1 = __builtin_fmaf(pl[1*128+k], w, a1);
      a2 = __builtin_fmaf(pl[2*128+k], w, a2);
      a3 = __builtin_fmaf(pl[3*128+k], w, a3);
      a4 = __builtin_fmaf(pl[4*128+k], w, a4);
      a5 = __builtin_fmaf(pl[5*128+k], w, a5);
      a6 = __builtin_fmaf(pl[6*128+k], w, a6);
      a7 = __builtin_fmaf(pl[7*128+k], w, a7);
    }
    float s = g1[t]*rsqrtf(1.0f + EPSV);
    float bb = b1[t], tb = be1[t];
    h1[0*256+t] = fmaxf(0.f, (a0+bb)*s + tb);
    h1[1*256+t] = fmaxf(0.f, (a1+bb)*s + tb);
    h1[2*256+t] = fmaxf(0.f, (a2+bb)*s + tb);
    h1[3*256+t] = fmaxf(0.f, (a3+bb)*s + tb);
    h1[4*256+t] = fmaxf(0.f, (a4+bb)*s + tb);
    h1[5*256+t] = fmaxf(0.f, (a5+bb)*s + tb);
    h1[6*256+t] = fmaxf(0.f, (a6+bb)*s + tb);
    h1[7*256+t] = fmaxf(0.f, (a7+bb)*s + tb);
  }
  __syncthreads();
  if (t < 128){
    float a0=0,a1=0,a2=0,a3=0,a4=0,a5=0,a6=0,a7=0;
    for (int k=0; k<256; k++){
      float w = w2[k*128 + t];
      a0 = __builtin_fmaf(h1[0*256+k], w, a0);
      a1 = __builtin_fmaf(h1[1*256+k], w, a1);
      a2 = __builtin_fmaf(h1[2*256+k], w, a2);
      a3 = __builtin_fmaf(h1[3*256+k], w, a3);
      a4 = __builtin_fmaf(h1[4*256+k], w, a4);
      a5 = __builtin_fmaf(h1[5*256+k], w, a5);
      a6 = __builtin_fmaf(h1[6*256+k], w, a6);
      a7 = __builtin_fmaf(h1[7*256+k], w, a7);
    }
    float s = g2[t]*rsqrtf(1.0f + EPSV);
    float bb = b2[t], tb = be2[t];
    h2l[0*128+t] = fmaxf(0.f, (a0+bb)*s + tb);
    h2l[1*128+t] = fmaxf(0.f, (a1+bb)*s + tb);
    h2l[2*128+t] = fmaxf(0.f, (a2+bb)*s + tb);
    h2l[3*128+t] = fmaxf(0.f, (a3+bb)*s + tb);
    h2l[4*128+t] = fmaxf(0.f, (a4+bb)*s + tb);
    h2l[5*128+t] = fmaxf(0.f, (a5+bb)*s + tb);
    h2l[6*128+t] = fmaxf(0.f, (a6+bb)*s + tb);
    h2l[7*128+t] = fmaxf(0.f, (a7+bb)*s + tb);
  }
  __syncthreads();
  if (t < 40){
    int g = t/5, c = t%5;
    float s = 0.f;
    for (int k=0; k<128; k++) s = __builtin_fmaf(h2l[g*128+k], w3[k*5+c], s);
    outp[t] = s + b3[c];
  }
}

extern "C" void kernel_launch(void* const* d_in, const int* in_sizes, int n_in,
                              void* d_out, int out_size, void* d_ws, size_t ws_size,
                              hipStream_t stream)
{
  const float* cnn   = (const float*)d_in[0];
  const float* morph = (const float*)d_in[1];
  const int*   eidx  = (const int*)d_in[2];
  const int*   batch = (const int*)d_in[3];
  const float* g1w = (const float*)d_in[4];
  const float* g1b = (const float*)d_in[5];
  const float* g2w = (const float*)d_in[6];
  const float* g2b = (const float*)d_in[7];
  const float* g3w = (const float*)d_in[8];
  const float* g3b = (const float*)d_in[9];
  const float* bn1g=(const float*)d_in[10], *bn1b=(const float*)d_in[11];
  const float* bn2g=(const float*)d_in[12], *bn2b=(const float*)d_in[13];
  const float* bn3g=(const float*)d_in[14], *bn3b=(const float*)d_in[15];
  const float* aw1=(const float*)d_in[16], *ab1=(const float*)d_in[17];
  const float* aw2=(const float*)d_in[18], *ab2=(const float*)d_in[19];
  const float* cw1=(const float*)d_in[20], *cb1=(const float*)d_in[21];
  const float* c1g=(const float*)d_in[22], *c1b=(const float*)d_in[23];
  const float* cw2=(const float*)d_in[24], *cb2=(const float*)d_in[25];
  const float* c2g=(const float*)d_in[26], *c2b=(const float*)d_in[27];
  const float* cw3=(const float*)d_in[28], *cb3=(const float*)d_in[29];

  const int N = in_sizes[3];
  const int E = in_sizes[2] / 2;
  const int CNNW = in_sizes[0] / N;   // 768
  const int MOR  = in_sizes[1] / N;   // 6
  const int D = CNNW + MOR;           // 774
  const int Dpad1 = ((D + 63)/64)*64; // 832

  char* p = (char*)d_ws;
  auto alloc = [&](size_t bytes)->char* {
    char* r = p; p += (bytes + 255) & ~(size_t)255; return r;
  };
  unsigned short* hbuf = (unsigned short*)alloc((size_t)N*128*2);  // bf16 h
  unsigned short* x1   = (unsigned short*)alloc((size_t)N*128*2);  // bf16 x1 / x_out
  unsigned short* x2   = (unsigned short*)alloc((size_t)N*128*2);  // bf16 x2
  float* dinv  = (float*)alloc((size_t)N*4);
  char* zstart = p;
  int* deg      = (int*)alloc((size_t)N*4);
  float* denom  = (float*)alloc(8*4);
  float* pooled = (float*)alloc(8*128*4);
  size_t zbytes = (size_t)(p - zstart);
  int* row_start=(int*)alloc((size_t)(N+1)*4);
  int* cursor  = (int*)alloc((size_t)N*4);
  int2* csr_ew = (int2*)alloc((size_t)E*8);
  int* bsums   = (int*)alloc(4096);
  unsigned short* w1T = (unsigned short*)alloc((size_t)128*Dpad1*2);
  unsigned short* w2T = (unsigned short*)alloc((size_t)128*128*2);
  unsigned short* w3T = (unsigned short*)alloc((size_t)128*128*2);
  unsigned short* aw1hiT = (unsigned short*)alloc((size_t)128*128*2);
  unsigned short* aw1loT = (unsigned short*)alloc((size_t)128*128*2);

  hipMemsetAsync(zstart, 0, zbytes, stream);

  const int* srcp = eidx;
  const int* dstp = eidx + E;

  int gE = (E + 255)/256;
  int B  = (N + 1023)/1024;
  int gMfma = (N + 127)/128;
  int gGat  = (N + 15)/16;

  // CSR build (+ fused edge-weight precompute)
  hist_kernel<<<dim3(gE), dim3(256), 0, stream>>>(dstp, deg, E);
  scan_partial<<<dim3(B), dim3(256), 0, stream>>>(deg, bsums, N);
  scan_bsums<<<dim3(1), dim3(64), 0, stream>>>(bsums, row_start, B, N, E);
  scan_final<<<dim3(B), dim3(256), 0, stream>>>(deg, bsums, row_start, cursor, dinv, N);
  scatter_kernel<<<dim3(gE), dim3(256), 0, stream>>>(srcp, dstp, cursor, dinv, csr_ew, E);

  // weight pre-convert
  wsplit_kernel<<<dim3((Dpad1+255)/256, 128), dim3(256), 0, stream>>>(g1w, w1T, D, Dpad1);
  wsplit_all<<<dim3(1, 128, 3), dim3(128), 0, stream>>>(g2w, g3w, aw1, w2T, w3T, aw1hiT, aw1loT);

  // GCN layer 1 (concat fp32 input)
  gemm_mfma_kernel<<<dim3(gMfma), dim3(256), 0, stream>>>(cnn, morph, w1T, hbuf, N, CNNW, MOR, Dpad1);
  gather_kernel<<<dim3(gGat), dim3(256), 0, stream>>>(hbuf, dinv, row_start, csr_ew,
      g1b, bn1g, bn1b, (const unsigned short*)nullptr, (const unsigned short*)nullptr, x1, N, 0);
  // GCN layer 2 (bf16 input)
  gemm_bf16_kernel<<<dim3(gMfma), dim3(256), 0, stream>>>(x1, w2T, hbuf, N);
  gather_kernel<<<dim3(gGat), dim3(256), 0, stream>>>(hbuf, dinv, row_start, csr_ew,
      g2b, bn2g, bn2b, (const unsigned short*)nullptr, (const unsigned short*)nullptr, x2, N, 0);
  // GCN layer 3 -> x_out = x1+x2+x3 into x1
  gemm_bf16_kernel<<<dim3(gMfma), dim3(256), 0, stream>>>(x2, w3T, hbuf, N);
  gather_kernel<<<dim3(gGat), dim3(256), 0, stream>>>(hbuf, dinv, row_start, csr_ew,
      g3b, bn3g, bn3b, x1, x2, x1, N, 2);

  // attention + softmax-denominator + pooling (fused)
  att_pool_kernel<<<dim3(gMfma), dim3(256), 0, stream>>>(x1, aw1hiT, aw1loT,
      ab1, aw2, ab2, batch, pooled, denom, N);

  classifier_kernel<<<dim3(1), dim3(256), 0, stream>>>(pooled, denom,
      cw1, cb1, c1g, c1b, cw2, cb2, c2g, c2b, cw3, cb3, (float*)d_out);
}